// Round 6
// baseline (1385.991 us; speedup 1.0000x reference)
//
#include <hip/hip_runtime.h>
#include <hip/hip_bf16.h>
#include <cstdint>
#include <cstddef>

typedef __bf16 bft;
typedef __bf16 bf16x8 __attribute__((ext_vector_type(8)));
typedef __bf16 bf16x4 __attribute__((ext_vector_type(4)));
typedef float  f32x4  __attribute__((ext_vector_type(4)));

#define MFMA(a, b, c) __builtin_amdgcn_mfma_f32_16x16x32_bf16(a, b, c, 0, 0, 0)
// in-wave LDS write->read ordering (wave-private regions, no block barrier)
#define LDS_FENCE() asm volatile("s_waitcnt lgkmcnt(0)" ::: "memory")

constexpr float SCALE = 0.17677669529663689f;  // hd^-0.5, hd=32
constexpr float INVS  = 5.656854249492381f;    // 1/SCALE (bias uses raw q)

// ---------------- fp32 -> bf16 convert (weights only) ----------------
__global__ __launch_bounds__(256) void cvt_kernel(const float* __restrict__ s,
                                                  bft* __restrict__ d, int n) {
  int stride = gridDim.x * blockDim.x;
  for (int i = blockIdx.x * blockDim.x + threadIdx.x; i * 4 < n; i += stride) {
    const float4 v = *reinterpret_cast<const float4*>(s + (size_t)i * 4);
    bf16x4 o = {(bft)v.x, (bft)v.y, (bft)v.z, (bft)v.w};
    *reinterpret_cast<bf16x4*>(d + (size_t)i * 4) = o;
  }
}

// ================= fused window kernel, v3 =================
// 1 block = 1 window, 4 waves, 2 head-passes (h = wv + 4p). P1 is STREAMED:
// kk-outer loop loads af[4] (16 VGPRs) from global per k-slice; accumulators
// stay in registers (sweep A: Q,K 4 tiles; sweep B: V 2 tiles) -> no 128-reg
// x array -> no spill (round-5 lesson: global-backed regs spill, LDS-backed
// stream). All LDS regions wave-private; zero block barriers in the pass loop.
// SPLIT=1: O -> global ws (bf16), proj done by proj_gemm kernel.
//          LDS 54,272 B -> 3 blocks/CU (3 waves/SIMD).
// SPLIT=0: O -> LDS, in-kernel proj tail (v2 structure). LDS 77,824 B.
template <int SPLIT>
__global__ __launch_bounds__(256, SPLIT ? 3 : 2) void win_k(
    const float* __restrict__ X, const bft* __restrict__ Wq,
    const float* __restrict__ Bq, const bft* __restrict__ Wp,
    const float* __restrict__ Bp, const float* __restrict__ rph,
    const float* __restrict__ rpw, float* __restrict__ Out,
    bft* __restrict__ Ows) {
  // layout: [0,18432): 4 wave-slots {Q 64x36, K 64x36} (P reuses, stride 68)
  // SPLIT: [18432,27136): 4 wave-slots V^T [32][68]
  // FUSED: [18432,38912): 8 head-slots {V^T [32][68] | O [64][40]} (2560 ea)
  __shared__ alignas(16) bft lds[SPLIT ? 27136 : 38912];

  const int t = threadIdx.x, lane = t & 63, wv = t >> 6;
  const int l15 = lane & 15, l4 = lane >> 4;
  const int win = blockIdx.x;
  const int b = win >> 8, wh = (win >> 4) & 15, ww = win & 15;
  const float* xw =
      X + ((size_t)b * 16384 + (size_t)(wh * 8) * 128 + ww * 8) * 256;

  // rel-pos table B-frags (cols = table row idx 0..14; col 15 = 0)
  bf16x8 rhf = {}, rwf = {};
  if (l15 < 15) {
    const float* th = rph + l15 * 32 + l4 * 8;
    const float* tw = rpw + l15 * 32 + l4 * 8;
#pragma unroll
    for (int j = 0; j < 8; ++j) {
      rhf[j] = (bft)(th[j] * INVS);
      rwf[j] = (bft)(tw[j] * INVS);
    }
  }

  const int qb = wv * 4608, kb = qb + 2304;

  auto load_af = [&](int kk, bf16x8 af[4]) {
#pragma unroll
    for (int m = 0; m < 4; ++m) {
      const int tok = m * 16 + l15;
      const float* cp =
          xw + (size_t)((tok >> 3) * 128 + (tok & 7)) * 256 + kk * 32 + l4 * 8;
      float4 a = *reinterpret_cast<const float4*>(cp);
      float4 c2 = *reinterpret_cast<const float4*>(cp + 4);
      bf16x8 f = {(bft)a.x, (bft)a.y, (bft)a.z, (bft)a.w,
                  (bft)c2.x, (bft)c2.y, (bft)c2.z, (bft)c2.w};
      af[m] = f;
    }
  };

#pragma unroll 1
  for (int p = 0; p < 2; ++p) {
    const int h = wv + p * 4;
    const int vb = SPLIT ? (18432 + wv * 2176) : (18432 + h * 2560);

    // ---- P1 sweep A: Q,K (4 n-tiles), kk-outer streamed ----
    {
      f32x4 acc[4][4] = {};  // [tile tq][m]
#pragma unroll 2
      for (int kk = 0; kk < 8; ++kk) {
        bf16x8 af[4];
        load_af(kk, af);
#pragma unroll
        for (int tq = 0; tq < 4; ++tq) {
          const int n0 = (tq >> 1) * 256 + h * 32 + (tq & 1) * 16;
          bf16x8 bw = *reinterpret_cast<const bf16x8*>(
              &Wq[(size_t)(n0 + l15) * 256 + kk * 32 + l4 * 8]);
#pragma unroll
          for (int m = 0; m < 4; ++m) acc[tq][m] = MFMA(af[m], bw, acc[tq][m]);
        }
      }
#pragma unroll
      for (int tq = 0; tq < 4; ++tq) {
        const int comp = tq >> 1, half = tq & 1;
        const float bias = Bq[comp * 256 + h * 32 + half * 16 + l15];
        const int base = (comp == 0) ? qb : kb;
        const float sc = (comp == 0) ? SCALE : 1.0f;
#pragma unroll
        for (int m = 0; m < 4; ++m)
#pragma unroll
          for (int r = 0; r < 4; ++r)
            lds[base + (m * 16 + l4 * 4 + r) * 36 + half * 16 + l15] =
                (bft)((acc[tq][m][r] + bias) * sc);
      }
    }

    // ---- P1 sweep B: V (2 n-tiles) -> V^T [c 32][tok 64] stride 68 ----
    {
      f32x4 av[2][4] = {};
#pragma unroll 2
      for (int kk = 0; kk < 8; ++kk) {
        bf16x8 af[4];
        load_af(kk, af);
#pragma unroll
        for (int tv = 0; tv < 2; ++tv) {
          const int n0 = 512 + h * 32 + tv * 16;
          bf16x8 bw = *reinterpret_cast<const bf16x8*>(
              &Wq[(size_t)(n0 + l15) * 256 + kk * 32 + l4 * 8]);
#pragma unroll
          for (int m = 0; m < 4; ++m) av[tv][m] = MFMA(af[m], bw, av[tv][m]);
        }
      }
#pragma unroll
      for (int tv = 0; tv < 2; ++tv) {
        const float bias = Bq[512 + h * 32 + tv * 16 + l15];
#pragma unroll
        for (int m = 0; m < 4; ++m) {
          bf16x4 pk = {(bft)(av[tv][m][0] + bias), (bft)(av[tv][m][1] + bias),
                       (bft)(av[tv][m][2] + bias), (bft)(av[tv][m][3] + bias)};
          *reinterpret_cast<bf16x4*>(
              &lds[vb + (tv * 16 + l15) * 68 + m * 16 + l4 * 4]) = pk;
        }
      }
    }
    LDS_FENCE();  // Q/K/V writes -> own-wave fragment reads

    // ---- P2: attention for head h (wave-private) ----
    bf16x8 qf[4], kf[4];
#pragma unroll
    for (int i = 0; i < 4; ++i) {
      bf16x4 lo, hi;
      lo = *reinterpret_cast<const bf16x4*>(&lds[qb + (i * 16 + l15) * 36 + l4 * 8]);
      hi = *reinterpret_cast<const bf16x4*>(&lds[qb + (i * 16 + l15) * 36 + l4 * 8 + 4]);
      qf[i] = __builtin_shufflevector(lo, hi, 0, 1, 2, 3, 4, 5, 6, 7);
      lo = *reinterpret_cast<const bf16x4*>(&lds[kb + (i * 16 + l15) * 36 + l4 * 8]);
      hi = *reinterpret_cast<const bf16x4*>(&lds[kb + (i * 16 + l15) * 36 + l4 * 8 + 4]);
      kf[i] = __builtin_shufflevector(lo, hi, 0, 1, 2, 3, 4, 5, 6, 7);
    }
    f32x4 s[4][4], gh[4], gw[4];
#pragma unroll
    for (int i = 0; i < 4; ++i) {
      f32x4 z = {};
      gh[i] = MFMA(qf[i], rhf, z);
      gw[i] = MFMA(qf[i], rwf, z);
#pragma unroll
      for (int j = 0; j < 4; ++j) {
        f32x4 z2 = {};
        s[i][j] = MFMA(qf[i], kf[j], z2);
      }
    }
#pragma unroll
    for (int i = 0; i < 4; ++i)
#pragma unroll
      for (int r = 0; r < 4; ++r) {
        const int row = i * 16 + l4 * 4 + r;
        const int qy = row >> 3, qx = row & 7;
        const float bwv = __shfl(gw[i][r], (lane & 48) + (qx + 7 - (l15 & 7)));
        float v0[4], mx = -3.0e38f;
#pragma unroll
        for (int j = 0; j < 4; ++j) {
          const float bh =
              __shfl(gh[i][r], (lane & 48) + (qy + 7 - (j * 2 + (l15 >> 3))));
          v0[j] = s[i][j][r] + bh + bwv;
          mx = fmaxf(mx, v0[j]);
        }
        mx = fmaxf(mx, __shfl_xor(mx, 1));
        mx = fmaxf(mx, __shfl_xor(mx, 2));
        mx = fmaxf(mx, __shfl_xor(mx, 4));
        mx = fmaxf(mx, __shfl_xor(mx, 8));
        float sum = 0.f;
#pragma unroll
        for (int j = 0; j < 4; ++j) {
          v0[j] = __expf(v0[j] - mx);
          sum += v0[j];
        }
        sum += __shfl_xor(sum, 1);
        sum += __shfl_xor(sum, 2);
        sum += __shfl_xor(sum, 4);
        sum += __shfl_xor(sum, 8);
        const float inv = 1.0f / sum;
#pragma unroll
        for (int j = 0; j < 4; ++j)
          lds[qb + row * 68 + j * 16 + l15] = (bft)(v0[j] * inv);
      }
    LDS_FENCE();  // P writes -> own-wave pf reads
    // PV: O(64x32) = P(64x64) @ V(64x32)
    bf16x8 pf[4][2], vf[2][2];
#pragma unroll
    for (int i = 0; i < 4; ++i)
#pragma unroll
      for (int kc = 0; kc < 2; ++kc) {
        bf16x4 lo = *reinterpret_cast<const bf16x4*>(
            &lds[qb + (i * 16 + l15) * 68 + kc * 32 + l4 * 8]);
        bf16x4 hi = *reinterpret_cast<const bf16x4*>(
            &lds[qb + (i * 16 + l15) * 68 + kc * 32 + l4 * 8 + 4]);
        pf[i][kc] = __builtin_shufflevector(lo, hi, 0, 1, 2, 3, 4, 5, 6, 7);
      }
#pragma unroll
    for (int j2 = 0; j2 < 2; ++j2)
#pragma unroll
      for (int kc = 0; kc < 2; ++kc) {
        bf16x4 lo = *reinterpret_cast<const bf16x4*>(
            &lds[vb + (j2 * 16 + l15) * 68 + kc * 32 + l4 * 8]);
        bf16x4 hi = *reinterpret_cast<const bf16x4*>(
            &lds[vb + (j2 * 16 + l15) * 68 + kc * 32 + l4 * 8 + 4]);
        vf[j2][kc] = __builtin_shufflevector(lo, hi, 0, 1, 2, 3, 4, 5, 6, 7);
      }
    f32x4 o[4][2] = {};
#pragma unroll
    for (int i = 0; i < 4; ++i)
#pragma unroll
      for (int j2 = 0; j2 < 2; ++j2) {
        o[i][j2] = MFMA(pf[i][0], vf[j2][0], o[i][j2]);
        o[i][j2] = MFMA(pf[i][1], vf[j2][1], o[i][j2]);
      }
    if (SPLIT) {
      // O -> global ws, canonical [win*64+tok][head*32+c] bf16
      bft* ob = Ows + (size_t)win * 16384 + h * 32;
#pragma unroll
      for (int i = 0; i < 4; ++i)
#pragma unroll
        for (int j2 = 0; j2 < 2; ++j2)
#pragma unroll
          for (int r = 0; r < 4; ++r)
            ob[(size_t)(i * 16 + l4 * 4 + r) * 256 + j2 * 16 + l15] =
                (bft)o[i][j2][r];
    } else {
      // O overwrites V slot h: [64][40]
#pragma unroll
      for (int i = 0; i < 4; ++i)
#pragma unroll
        for (int j2 = 0; j2 < 2; ++j2)
#pragma unroll
          for (int r = 0; r < 4; ++r)
            lds[vb + (i * 16 + l4 * 4 + r) * 40 + j2 * 16 + l15] =
                (bft)o[i][j2][r];
    }
  }

  if (!SPLIT) {
    __syncthreads();  // all O slots ready (only cross-wave dependency)
    f32x4 po[4][4] = {};
#pragma unroll
    for (int sH = 0; sH < 8; ++sH) {
      bf16x8 oa[4];
#pragma unroll
      for (int m = 0; m < 4; ++m)
        oa[m] = *reinterpret_cast<const bf16x8*>(
            &lds[18432 + sH * 2560 + (m * 16 + l15) * 40 + l4 * 8]);
#pragma unroll
      for (int n = 0; n < 4; ++n) {
        bf16x8 wb = *reinterpret_cast<const bf16x8*>(
            &Wp[(size_t)(wv * 64 + n * 16 + l15) * 256 + sH * 32 + l4 * 8]);
#pragma unroll
        for (int m = 0; m < 4; ++m) po[m][n] = MFMA(oa[m], wb, po[m][n]);
      }
    }
    float pbias[4];
#pragma unroll
    for (int n = 0; n < 4; ++n) pbias[n] = Bp[wv * 64 + n * 16 + l15];
    float* ob =
        Out + ((size_t)b * 16384 + (size_t)(wh * 8) * 128 + ww * 8) * 256;
#pragma unroll
    for (int m = 0; m < 4; ++m)
#pragma unroll
      for (int r = 0; r < 4; ++r) {
        const int tok = m * 16 + l4 * 4 + r;
        float* og = ob + ((size_t)(tok >> 3) * 128 + (tok & 7)) * 256;
#pragma unroll
        for (int n = 0; n < 4; ++n)
          og[wv * 64 + n * 16 + l15] = po[m][n][r] + pbias[n];
      }
  }
}

// ---------------- proj GEMM + window_reverse (SPLIT path) ----------------
// A = Ows bf16 [262144][256]; B = proj_w bf16 [256][256] (as B^T); fp32 out.
__global__ __launch_bounds__(256) void proj_gemm(const bft* __restrict__ A,
    const bft* __restrict__ Bm, const float* __restrict__ bias,
    float* __restrict__ Out) {
  constexpr int RS = 72;
  __shared__ alignas(16) bft As[128 * RS];
  __shared__ alignas(16) bft Bs[128 * RS];
  const int t = threadIdx.x;
  const int lane = t & 63, wv = t >> 6;
  const int wy = wv >> 1, wx = wv & 1;
  const int l15 = lane & 15, l4 = lane >> 4;
  const int m0 = blockIdx.x * 128, n0 = blockIdx.y * 128;
  const int srow = t >> 3, sc = (t & 7) * 8;
  f32x4 acc[4][4] = {};
  for (int k0 = 0; k0 < 256; k0 += 64) {
#pragma unroll
    for (int i2 = 0; i2 < 4; ++i2) {
      int r = i2 * 32 + srow;
      *reinterpret_cast<bf16x8*>(&As[r * RS + sc]) =
          *reinterpret_cast<const bf16x8*>(&A[(size_t)(m0 + r) * 256 + k0 + sc]);
      *reinterpret_cast<bf16x8*>(&Bs[r * RS + sc]) =
          *reinterpret_cast<const bf16x8*>(&Bm[(size_t)(n0 + r) * 256 + k0 + sc]);
    }
    __syncthreads();
#pragma unroll
    for (int kc = 0; kc < 2; ++kc) {
      bf16x8 af[4], bfr[4];
#pragma unroll
      for (int i = 0; i < 4; ++i)
        af[i] = *reinterpret_cast<const bf16x8*>(
            &As[(wy * 64 + i * 16 + l15) * RS + kc * 32 + l4 * 8]);
#pragma unroll
      for (int j = 0; j < 4; ++j)
        bfr[j] = *reinterpret_cast<const bf16x8*>(
            &Bs[(wx * 64 + j * 16 + l15) * RS + kc * 32 + l4 * 8]);
#pragma unroll
      for (int i = 0; i < 4; ++i)
#pragma unroll
        for (int j = 0; j < 4; ++j) acc[i][j] = MFMA(af[i], bfr[j], acc[i][j]);
    }
    __syncthreads();
  }
  const int colb = n0 + wx * 64;
#pragma unroll
  for (int i = 0; i < 4; ++i) {
#pragma unroll
    for (int r = 0; r < 4; ++r) {
      int row = m0 + wy * 64 + i * 16 + l4 * 4 + r;
      int win = row >> 6, tok = row & 63;
      int b = win >> 8, wh = (win >> 4) & 15, ww = win & 15;
      int y = tok >> 3, x = tok & 7;
      size_t g = ((size_t)b << 14) + ((size_t)(wh * 8 + y) << 7) + (ww * 8 + x);
#pragma unroll
      for (int j = 0; j < 4; ++j) {
        int col = colb + j * 16 + l15;
        Out[g * 256 + col] = acc[i][j][r] + bias[col];
      }
    }
  }
}

extern "C" void kernel_launch(void* const* d_in, const int* in_sizes, int n_in,
                              void* d_out, int out_size, void* d_ws,
                              size_t ws_size, hipStream_t stream) {
  const float* x      = (const float*)d_in[0];
  const float* qkv_w  = (const float*)d_in[1];
  const float* qkv_b  = (const float*)d_in[2];
  const float* proj_w = (const float*)d_in[3];
  const float* proj_b = (const float*)d_in[4];
  const float* rph    = (const float*)d_in[5];
  const float* rpw    = (const float*)d_in[6];
  float* out = (float*)d_out;

  constexpr size_t O_OFF = 524288;                       // after bf16 weights
  constexpr size_t NEED_SPLIT = O_OFF + 134217728ull;    // + O bf16 (134 MB)
  if (ws_size < 524288) return;
  bft* qw = (bft*)d_ws;                    // qkv_w bf16: 196608 elems
  bft* pw = (bft*)((char*)d_ws + 393216);  // proj_w bf16: 65536 elems
  bft* Ows = (bft*)((char*)d_ws + O_OFF);  // attn-out bf16 (SPLIT only)

  cvt_kernel<<<192, 256, 0, stream>>>(qkv_w, qw, 196608);
  cvt_kernel<<<64, 256, 0, stream>>>(proj_w, pw, 65536);
  if (ws_size >= NEED_SPLIT) {
    win_k<1><<<4096, 256, 0, stream>>>(x, qw, qkv_b, pw, proj_b, rph, rpw,
                                       out, Ows);
    proj_gemm<<<dim3(2048, 2), 256, 0, stream>>>(Ows, pw, proj_b, out);
  } else {
    win_k<0><<<4096, 256, 0, stream>>>(x, qw, qkv_b, pw, proj_b, rph, rpw,
                                       out, Ows);
  }
}